// Round 7
// baseline (1217.980 us; speedup 1.0000x reference)
//
#include <hip/hip_runtime.h>
#include <math.h>

typedef unsigned int   uint32;
typedef unsigned short ushort16;
typedef __attribute__((ext_vector_type(8))) short  short8;   // 8 bf16 (MFMA A/B frag)
typedef __attribute__((ext_vector_type(4))) float  floatx4;  // MFMA C/D frag

// Problem dims
#define Bb   512
#define QLn  128
#define ALn  512
#define En   300
#define Fn   400
#define OW   416      // packed output width: 400 real + 16 zero (832 B = 13*64)
#define EPAD 320      // e padded 300 -> 320 per shift; K_total = 3*320 = 960
#define NV   50001

typedef const __attribute__((address_space(1))) unsigned int guint_t;
typedef __attribute__((address_space(3))) unsigned int luint_t;
#define GLDS16(g, l) __builtin_amdgcn_global_load_lds((guint_t*)(g), (luint_t*)(l), 16, 0, 0)

// s_waitcnt immediates (gfx9 encoding: vmcnt[3:0]=b3:0, expcnt=b6:4, lgkmcnt=b11:8, vmcnt[5:4]=b15:14)
#define WVM8   0x0F78   // vmcnt(8),  exp/lgkm don't-care
#define WVM6   0x0F76   // vmcnt(6)
#define WVM0   0x0F70   // vmcnt(0)
#define WLGKM0 0xC07F   // lgkmcnt(0), vm don't-care

static __device__ __forceinline__ float bf_lo(uint32 u) { return __uint_as_float(u << 16); }
static __device__ __forceinline__ float bf_hi(uint32 u) { return __uint_as_float(u & 0xffff0000u); }
static __device__ __forceinline__ ushort16 f2bf(float f) {
    uint32 u = __float_as_uint(f);
    uint32 r = (u + 0x7fffu + ((u >> 16) & 1u)) >> 16;   // RNE
    return (ushort16)r;
}
static __device__ __forceinline__ uint32 pack2(float a, float b) {
    return (uint32)f2bf(a) | ((uint32)f2bf(b) << 16);
}

// ---------------------------------------------------------------------------
// embcvt: embbf[v][0..320) = bf16(emb[v][0..300)), e>=300 zero.
// ---------------------------------------------------------------------------
__global__ __launch_bounds__(128) void embcvt_kernel(
        const float* __restrict__ emb, char* __restrict__ embbf)
{
    const int r = blockIdx.x, j = threadIdx.x;
    const float* er = emb + (size_t)r * En;
    uint32* orow = (uint32*)(embbf + (size_t)r * 640);
    for (int d = j; d < 160; d += 128) {
        uint32 v = 0;
        if (d < 150) {
            float2 f2v = *(const float2*)(er + 2 * d);
            v = pack2(f2v.x, f2v.y);
        }
        orow[d] = v;
    }
}

// ---------------------------------------------------------------------------
// prep_wt: Wt2[f][p] = W[f][e*3+kk] (p = kk*320+e), bf16, zero pad; bias2.
// ---------------------------------------------------------------------------
__global__ __launch_bounds__(256) void prep_wt(
        const float* __restrict__ W, const float* __restrict__ cb,
        ushort16* __restrict__ Wt2, float* __restrict__ bias2)
{
    const int f = blockIdx.x, t = threadIdx.x;
    for (int p2 = t; p2 < 480; p2 += 256) {
        int p = 2 * p2;
        float v0 = 0.f, v1 = 0.f;
        if (f < Fn) {
            int kk = p / EPAD, e = p - kk * EPAD;
            if (e < En)     v0 = W[(size_t)f * 900 + e * 3 + kk];
            if (e + 1 < En) v1 = W[(size_t)f * 900 + (e + 1) * 3 + kk];
        }
        *(uint32*)&Wt2[(size_t)f * 960 + p] = pack2(v0, v1);
    }
    if (t == 0) bias2[f] = (f < Fn) ? cb[f] : 0.f;
}

// ---------------------------------------------------------------------------
// prep_wp: Wp2[g][p] = sum_f U[f][g]*W[f][p900], fp32 accum, bf16 store.
// ---------------------------------------------------------------------------
__global__ __launch_bounds__(256) void prep_wp(
        const float* __restrict__ W, const float* __restrict__ U,
        ushort16* __restrict__ Wp2)
{
    __shared__ float Wl[400 * 32];
    const int t = threadIdx.x;
    const int pc = blockIdx.x, gc = blockIdx.y;
    const int kk = (pc * 32) / EPAD, e0 = pc * 32 - kk * EPAD;

    for (int i = t; i < 400 * 32; i += 256) {
        int f = i >> 5, j = i & 31, e = e0 + j;
        Wl[i] = (e < En) ? W[(size_t)f * 900 + e * 3 + kk] : 0.f;
    }
    __syncthreads();

    const int g = gc * 128 + (t >> 1);
    const int jh = (t & 1) * 16;
    float acc[16];
#pragma unroll
    for (int k = 0; k < 16; ++k) acc[k] = 0.f;

    for (int f = 0; f < Fn; ++f) {
        float uf = 0.f;
        if (g < Fn) uf = U[(size_t)f * Fn + g];
        const float* wl = Wl + f * 32 + jh;
#pragma unroll
        for (int k = 0; k < 16; ++k) acc[k] = fmaf(uf, wl[k], acc[k]);
    }
    ushort16* orow = Wp2 + (size_t)g * 960 + pc * 32 + jh;
#pragma unroll
    for (int k = 0; k < 16; k += 2)
        *(uint32*)&orow[k] = pack2(acc[k], acc[k + 1]);
}

__global__ __launch_bounds__(256) void prep_bp(
        const float* __restrict__ cb, const float* __restrict__ U,
        float* __restrict__ bp2)
{
    __shared__ float cbl[Fn];
    const int t = threadIdx.x;
    for (int f = t; f < Fn; f += 256) cbl[f] = cb[f];
    __syncthreads();
#pragma unroll
    for (int h = 0; h < 2; ++h) {
        int g = t + h * 256;
        float s = 0.f;
        if (g < Fn)
            for (int f = 0; f < Fn; ++f) s += cbl[f] * U[(size_t)f * Fn + g];
        bp2[g] = s;
    }
}

// ---------------------------------------------------------------------------
// conv_task: ONE WAVE computes a 64-row x (NF*16)-col output tile, K=960.
// Fully decoupled: wave-private LDS ping/pong (2 x 8 KB), global_load_lds
// staging, manual s_waitcnt vmcnt(N)/lgkmcnt(0) — NO barriers anywhere, so
// prefetch loads stay in flight across k-steps (AITER-style pipeline).
// XOR swizzle: source chunk cg written to slot lane&3; reads use
// chunkOff = ((fq + (fm>>1))&3)*16 with 64 B row stride (R6-verified, 0 confl).
// ---------------------------------------------------------------------------
template<int NF>
static __device__ void conv_task(
        const int* __restrict__ tok, int l0, int L,
        const char* __restrict__ embbf,
        const char* __restrict__ W,      // [512][960] bf16, row stride 1920
        const float* __restrict__ biasv, int col0,
        ushort16* __restrict__ ob,       // out + row0*OW
        char* ldsW)                      // 16 KB wave-private
{
    const int lane = threadIdx.x & 63;
    const int fm = lane & 15, fq4 = lane >> 4;
    const int cg = ((lane & 3) - ((lane >> 3) & 3)) & 3;
    const int srow = lane >> 2;          // 0..15 (staging row within 16-group)
    const int chunkOff = ((fq4 + (fm >> 1)) & 3) * 16;

    // per-lane gathered A source pointers: group i holds rows i*16+srow
    const char* pA[4][3];
#pragma unroll
    for (int i = 0; i < 4; ++i)
#pragma unroll
        for (int kk = 0; kk < 3; ++kk) {
            const int pos = l0 + i * 16 + srow - 1 + kk;
            const int tk = (pos >= 0 && pos < L) ? tok[pos] : 0;
            pA[i][kk] = embbf + (size_t)tk * 640 + cg * 16;
        }
    const char* pB[NF];
#pragma unroll
    for (int i = 0; i < NF; ++i)
        pB[i] = W + (size_t)(col0 + i * 16 + srow) * 1920 + cg * 16;

    floatx4 acc[4][NF];
    const floatx4 zz = {0.f, 0.f, 0.f, 0.f};
#pragma unroll
    for (int m = 0; m < 4; ++m)
#pragma unroll
        for (int n = 0; n < NF; ++n) acc[m][n] = zz;

    const char* rdB = ldsW + fm * 64 + chunkOff;

    // prologue: steps 0,1 -> buffers 0,1 (kk=0 for both)
#pragma unroll
    for (int s = 0; s < 2; ++s) {
        const int buf = s * 8192, ko = s * 64;
#pragma unroll
        for (int i = 0; i < 4; ++i)  GLDS16(pA[i][0] + ko, ldsW + buf + i * 1024);
#pragma unroll
        for (int i = 0; i < NF; ++i) GLDS16(pB[i] + ko, ldsW + buf + 4096 + i * 1024);
    }

    // steady-state: 30 flat k-steps (kk = s/10, ks = s%10)
#pragma unroll
    for (int s = 0; s < 30; ++s) {
        const int buf = (s & 1) * 8192;
        if (s < 29) __builtin_amdgcn_s_waitcnt(NF == 4 ? WVM8 : WVM6);
        else        __builtin_amdgcn_s_waitcnt(WVM0);

        short8 af[4], bf[NF];
#pragma unroll
        for (int m = 0; m < 4; ++m)
            af[m] = *(const short8*)(rdB + buf + m * 1024);
#pragma unroll
        for (int n = 0; n < NF; ++n)
            bf[n] = *(const short8*)(rdB + buf + 4096 + n * 1024);
        __builtin_amdgcn_s_waitcnt(WLGKM0);   // frags in regs; buffer free (WAR)

        if (s < 28) {
            const int s2 = s + 2, kk = s2 / 10, ko = (s2 - kk * 10) * 64;
#pragma unroll
            for (int i = 0; i < 4; ++i)
                GLDS16(pA[i][kk] + ko, ldsW + buf + i * 1024);
#pragma unroll
            for (int i = 0; i < NF; ++i)
                GLDS16(pB[i] + kk * 640 + ko, ldsW + buf + 4096 + i * 1024);
        }
#pragma unroll
        for (int m = 0; m < 4; ++m)
#pragma unroll
            for (int n = 0; n < NF; ++n)
                acc[m][n] = __builtin_amdgcn_mfma_f32_16x16x32_bf16(
                    af[m], bf[n], acc[m][n], 0, 0, 0);
    }

    // epilogue: +bias, bf16, store (C/D: col=lane&15, row=(lane>>4)*4+reg)
    float bn[NF];
#pragma unroll
    for (int n = 0; n < NF; ++n) bn[n] = biasv[col0 + n * 16 + fm];
#pragma unroll
    for (int m = 0; m < 4; ++m) {
        const int row = m * 16 + fq4 * 4;
#pragma unroll
        for (int n = 0; n < NF; ++n) {
            const int col = col0 + n * 16 + fm;
#pragma unroll
            for (int r = 0; r < 4; ++r)
                ob[(size_t)(row + r) * OW + col] = f2bf(acc[m][n][r] + bn[n]);
        }
    }
}

// col-slice table: j=0..4 -> (64j, NF4); j=5 -> (320, NF2); j=6 -> (352, NF4)
static __device__ __forceinline__ void run_slice(
        int j, const int* tok, int l0, int L, const char* embbf,
        const char* W, const float* biasv, ushort16* ob, char* ldsW)
{
    if (j == 5)      conv_task<2>(tok, l0, L, embbf, W, biasv, 320, ob, ldsW);
    else if (j == 6) conv_task<4>(tok, l0, L, embbf, W, biasv, 352, ob, ldsW);
    else             conv_task<4>(tok, l0, L, embbf, W, biasv, j * 64, ob, ldsW);
}

// conv_wave: 2 waves/block, each wave one independent task. 42 tasks/batch:
//  j42<28: A-conv: j=j42/4 (slice), rtp=j42%4, wave rt=rtp*2+w (8 rowtiles of 64)
//  else:   Q-convs: q=j42-28, j=q/2 slice, rt=q%2; wave w: 0->Wt2/qb, 1->Wp2/qpb
// XCD-affine: all 42 blocks of batch b land on XCD b&7.
__global__ __launch_bounds__(128) void conv_wave(
        const int* __restrict__ question, const int* __restrict__ answer,
        const char* __restrict__ embbf,
        const char* __restrict__ Wt2, const char* __restrict__ Wp2,
        const float* __restrict__ bias2, const float* __restrict__ bp2,
        ushort16* __restrict__ qb, ushort16* __restrict__ qpb,
        ushort16* __restrict__ ab, int nb, int nbB)
{
    __shared__ __align__(16) char lds[32768];
    const int bx = blockIdx.x;
    const int xcd = bx & 7;
    const int r = bx >> 3;
    const int j42 = r / nbB;
    const int bh = r - j42 * nbB;
    const int b = bh * 8 + xcd;
    if (b >= nb) return;
    const int w = threadIdx.x >> 6;
    char* ldsW = lds + w * 16384;

    if (j42 < 28) {
        const int j = j42 >> 2, rtp = j42 & 3;
        const int rt = rtp * 2 + w;
        run_slice(j, answer + (size_t)b * ALn, rt * 64, ALn, embbf,
                  Wt2, bias2, ab + ((size_t)b * ALn + rt * 64) * OW, ldsW);
    } else {
        const int q = j42 - 28;
        const int j = q >> 1, rt = q & 1;
        const char*  Wsel = w ? Wp2 : Wt2;
        const float* bsel = w ? bp2 : bias2;
        ushort16*    ob   = (w ? qpb : qb) + ((size_t)b * QLn + rt * 64) * OW;
        run_slice(j, question + (size_t)b * QLn, rt * 64, QLn, embbf,
                  Wsel, bsel, ob, ldsW);
    }
}

// ---------------------------------------------------------------------------
// fused_g: block (b, a-chunk c). Gpre = Q' A^T (K=416, cols 400..416 zeros).
// ---------------------------------------------------------------------------
__global__ __launch_bounds__(256) void fused_g(
        const ushort16* __restrict__ Qp,   // [nb][128][416]
        const ushort16* __restrict__ Av,   // [nb][512][416]
        float* __restrict__ rowPart,       // [nb][4][128]
        float* __restrict__ colMg,         // [nb][512]
        int nb)
{
    __shared__ __align__(16) char Qs[8192];
    __shared__ __align__(16) char Asl[8192];
    __shared__ float rowM2[128][2];
    __shared__ float colM2[128][2];

    const int t = threadIdx.x, lane = t & 63, w = t >> 6;
    const int bx = blockIdx.x;
    const int xcd = bx & 7, rest = bx >> 3;
    const int c = rest & 3, g = rest >> 2;
    const int T = g * 8 + xcd;
    if (T >= nb) return;
    const int b = T;
    const int wr = w >> 1, wc = w & 1;
    const int fm = lane & 15;
    const int cg = ((lane & 3) - ((lane >> 3) & 3)) & 3;
    const int srow = w * 16 + (lane >> 2);
    const int chunkOff = (((lane >> 4) + (fm >> 1)) & 3) * 16;

    const char* Qpb = (const char*)Qp + (size_t)b * 106496;
    const char* Ab  = (const char*)Av + (size_t)b * 425984 + (size_t)c * 106496;
    const char* srcQ = Qpb + (size_t)srow * 832 + cg * 16;
    const char* srcA = Ab  + (size_t)srow * 832 + cg * 16;
    char* QsW = Qs + w * 1024;
    char* AsW = Asl + w * 1024;

    floatx4 acc[4][4];
    const floatx4 zz = {0.f, 0.f, 0.f, 0.f};
#pragma unroll
    for (int m = 0; m < 4; ++m)
#pragma unroll
        for (int n = 0; n < 4; ++n) acc[m][n] = zz;

    for (int ks = 0; ks < 13; ++ks) {
        const int colb = ks * 64;
        __syncthreads();
        GLDS16(srcQ + colb,         QsW);
        GLDS16(srcQ + 53248 + colb, QsW + 4096);
        GLDS16(srcA + colb,         AsW);
        GLDS16(srcA + 53248 + colb, AsW + 4096);
        __syncthreads();

        short8 qa[4], aa_[4];
#pragma unroll
        for (int m = 0; m < 4; ++m)
            qa[m] = *(const short8*)(Qs + (wr * 64 + m * 16 + fm) * 64 + chunkOff);
#pragma unroll
        for (int n = 0; n < 4; ++n)
            aa_[n] = *(const short8*)(Asl + (wc * 64 + n * 16 + fm) * 64 + chunkOff);
#pragma unroll
        for (int m = 0; m < 4; ++m)
#pragma unroll
            for (int n = 0; n < 4; ++n)
                acc[m][n] = __builtin_amdgcn_mfma_f32_16x16x32_bf16(
                    qa[m], aa_[n], acc[m][n], 0, 0, 0);
    }

#pragma unroll
    for (int m = 0; m < 4; ++m)
#pragma unroll
        for (int r2 = 0; r2 < 4; ++r2) {
            float v = fmaxf(fmaxf(acc[m][0][r2], acc[m][1][r2]),
                            fmaxf(acc[m][2][r2], acc[m][3][r2]));
            v = fmaxf(v, __shfl_xor(v, 1));
            v = fmaxf(v, __shfl_xor(v, 2));
            v = fmaxf(v, __shfl_xor(v, 4));
            v = fmaxf(v, __shfl_xor(v, 8));
            if (fm == 0) rowM2[wr * 64 + m * 16 + (lane >> 4) * 4 + r2][wc] = v;
        }
#pragma unroll
    for (int n = 0; n < 4; ++n) {
        float v = -1e30f;
#pragma unroll
        for (int m = 0; m < 4; ++m)
#pragma unroll
            for (int r2 = 0; r2 < 4; ++r2) v = fmaxf(v, acc[m][n][r2]);
        v = fmaxf(v, __shfl_xor(v, 16));
        v = fmaxf(v, __shfl_xor(v, 32));
        if (lane < 16) colM2[wc * 64 + n * 16 + lane][wr] = v;
    }
    __syncthreads();
    if (t < 128) {
        rowPart[((size_t)b * 4 + c) * 128 + t] = fmaxf(rowM2[t][0], rowM2[t][1]);
        colMg[(size_t)b * 512 + c * 128 + t]   = fmaxf(colM2[t][0], colM2[t][1]);
    }
}

// ---------------------------------------------------------------------------
// pooling, split for parallelism: pool_parts (nb x 5 blocks) + pool_cos (nb)
// ---------------------------------------------------------------------------
static __device__ __forceinline__ float block_reduce_max(float v, volatile float* red) {
    int t = threadIdx.x;
    red[t] = v; __syncthreads();
    for (int s = 128; s > 0; s >>= 1) {
        if (t < s) red[t] = fmaxf(red[t], red[t + s]);
        __syncthreads();
    }
    float r = red[0]; __syncthreads();
    return r;
}
static __device__ __forceinline__ float block_reduce_sum(float v, volatile float* red) {
    int t = threadIdx.x;
    red[t] = v; __syncthreads();
    for (int s = 128; s > 0; s >>= 1) {
        if (t < s) red[t] = red[t] + red[t + s];
        __syncthreads();
    }
    float r = red[0]; __syncthreads();
    return r;
}

__global__ __launch_bounds__(256) void pool_parts(
        const ushort16* __restrict__ Qv,   // [nb][128][416]
        const ushort16* __restrict__ Av,   // [nb][512][416]
        const float* __restrict__ rowPart, // [nb][4][128]
        const float* __restrict__ colMg,   // [nb][512]
        float* __restrict__ rqv,           // [nb][416]
        float* __restrict__ rav)           // [nb][4][416]
{
    __shared__ float red[256];
    __shared__ float wgt[128];
    const int b = blockIdx.x, j = blockIdx.y, t = threadIdx.x;

    if (j == 0) {
        float v = -1e30f;
        if (t < QLn) {
            const float* rp = rowPart + (size_t)b * 512;
            float rm = fmaxf(fmaxf(rp[t], rp[128 + t]), fmaxf(rp[256 + t], rp[384 + t]));
            v = tanhf(rm);
        }
        float vmax = block_reduce_max(v, red);
        float ex = (t < QLn) ? __expf(v - vmax) : 0.f;
        float ssum = block_reduce_sum(ex, red);
        if (t < QLn) wgt[t] = ex / ssum;
        __syncthreads();
        float rq0 = 0.f, rq1 = 0.f;
        if (t < 208) {
            const uint32* Qb32 = (const uint32*)((const char*)Qv + (size_t)b * 106496);
#pragma unroll 4
            for (int q = 0; q < QLn; ++q) {
                float wv = wgt[q];
                uint32 u = Qb32[q * 208 + t];
                rq0 = fmaf(bf_lo(u), wv, rq0);
                rq1 = fmaf(bf_hi(u), wv, rq1);
            }
            rqv[(size_t)b * 416 + 2 * t]     = rq0;
            rqv[(size_t)b * 416 + 2 * t + 1] = rq1;
        }
    } else {
        float c0 = tanhf(colMg[(size_t)b * 512 + t]);
        float c1 = tanhf(colMg[(size_t)b * 512 + 256 + t]);
        float cmax = block_reduce_max(fmaxf(c0, c1), red);
        float e0 = __expf(c0 - cmax), e1 = __expf(c1 - cmax);
        float csum = block_reduce_sum(e0 + e1, red);
        const int a0 = (j - 1) * 128;
        if (t < 128)
            wgt[t] = __expf(tanhf(colMg[(size_t)b * 512 + a0 + t]) - cmax) / csum;
        __syncthreads();
        float ra0 = 0.f, ra1 = 0.f;
        if (t < 208) {
            const uint32* Ab32 = (const uint32*)((const char*)Av + (size_t)b * 425984);
#pragma unroll 4
            for (int a = 0; a < 128; ++a) {
                float wv = wgt[a];
                uint32 u = Ab32[(size_t)(a0 + a) * 208 + t];
                ra0 = fmaf(bf_lo(u), wv, ra0);
                ra1 = fmaf(bf_hi(u), wv, ra1);
            }
            rav[((size_t)b * 4 + (j - 1)) * 416 + 2 * t]     = ra0;
            rav[((size_t)b * 4 + (j - 1)) * 416 + 2 * t + 1] = ra1;
        }
    }
}

__global__ __launch_bounds__(256) void pool_cos(
        const float* __restrict__ rqv, const float* __restrict__ rav,
        float* __restrict__ out)
{
    __shared__ float red[256];
    const int b = blockIdx.x, t = threadIdx.x;
    float rq0 = 0.f, rq1 = 0.f, ra0 = 0.f, ra1 = 0.f;
    if (t < 208) {
        rq0 = rqv[(size_t)b * 416 + 2 * t];
        rq1 = rqv[(size_t)b * 416 + 2 * t + 1];
        const float* rb = rav + (size_t)b * 4 * 416;
#pragma unroll
        for (int p = 0; p < 4; ++p) {
            ra0 += rb[p * 416 + 2 * t];
            ra1 += rb[p * 416 + 2 * t + 1];
        }
    }
    float dd  = block_reduce_sum(rq0 * ra0 + rq1 * ra1, red);
    float qq  = block_reduce_sum(rq0 * rq0 + rq1 * rq1, red);
    float aam = block_reduce_sum(ra0 * ra0 + ra1 * ra1, red);
    if (t == 0) {
        float nq = fmaxf(sqrtf(qq), 1e-8f);
        float na = fmaxf(sqrtf(aam), 1e-8f);
        out[b] = dd / (nq * na);
    }
}

// ---------------------------------------------------------------------------
// launch — ws_size-adaptive balanced batch chunking (pure function of ws_size)
// ---------------------------------------------------------------------------
extern "C" void kernel_launch(void* const* d_in, const int* in_sizes, int n_in,
                              void* d_out, int out_size, void* d_ws, size_t ws_size,
                              hipStream_t stream)
{
    const int*   question = (const int*)d_in[0];
    const int*   answer   = (const int*)d_in[1];
    const float* emb      = (const float*)d_in[2];
    const float* conv_w   = (const float*)d_in[3];
    const float* conv_b   = (const float*)d_in[4];
    const float* U        = (const float*)d_in[5];
    float* out = (float*)d_out;
    char* ws = (char*)d_ws;

    const size_t WT2B   = (size_t)512 * 960 * 2;         // 983,040
    const size_t EMBB   = (size_t)NV * 640;              // 32,000,640
    const size_t FIXED0 = 2 * WT2B + 4096;               // 1,970,176
    const size_t FIXED  = FIXED0 + EMBB;                 // 33,970,816
    const size_t QB     = (size_t)QLn * OW * 2;          // 106,496
    const size_t AB     = (size_t)ALn * OW * 2;          // 425,984
    const size_t MXB    = 4096 + 1664 + 6656;            // rowP+colM+rqv+rav
    const size_t PER_B  = 2 * QB + AB + MXB;             // 651,392

    size_t avail = (ws_size > FIXED) ? (ws_size - FIXED) : 0;
    int CB = (int)(avail / PER_B);
    if (CB > Bb) CB = Bb;
    if (CB < 1)  CB = 1;
    int nch = (Bb + CB - 1) / CB;
    int CBe = (Bb + nch - 1) / nch;

    char*  wt2   = ws;
    char*  wp2   = ws + WT2B;
    float* bias2 = (float*)(ws + 2 * WT2B);
    float* bp2   = (float*)(ws + 2 * WT2B + 2048);
    char*  embbf = ws + FIXED0;
    char*  qb    = ws + FIXED;
    char*  qpb   = qb  + (size_t)CB * QB;
    char*  ab    = qpb + (size_t)CB * QB;
    float* rowP  = (float*)(ab + (size_t)CB * AB);
    float* colM  = rowP + (size_t)CB * 512;
    float* rqv   = colM + (size_t)CB * 512;
    float* rav   = rqv  + (size_t)CB * 416;

    embcvt_kernel<<<NV, 128, 0, stream>>>(emb, embbf);
    prep_wt<<<512, 256, 0, stream>>>(conv_w, conv_b, (ushort16*)wt2, bias2);
    prep_wp<<<dim3(30, 4), 256, 0, stream>>>(conv_w, U, (ushort16*)wp2);
    prep_bp<<<1, 256, 0, stream>>>(conv_b, U, bp2);

    for (int b0 = 0; b0 < Bb; b0 += CBe) {
        int nb = (Bb - b0 < CBe) ? (Bb - b0) : CBe;
        int nbB = (nb + 7) / 8;
        conv_wave<<<42 * nbB * 8, 128, 0, stream>>>(
            question + (size_t)b0 * QLn, answer + (size_t)b0 * ALn, embbf,
            wt2, wp2, bias2, bp2,
            (ushort16*)qb, (ushort16*)qpb, (ushort16*)ab, nb, nbB);

        int blocksG = ((nb + 7) / 8) * 8 * 4;
        fused_g<<<blocksG, 256, 0, stream>>>((const ushort16*)qpb, (const ushort16*)ab,
                                             rowP, colM, nb);
        pool_parts<<<dim3(nb, 5), 256, 0, stream>>>(
            (const ushort16*)qb, (const ushort16*)ab, rowP, colM, rqv, rav);
        pool_cos<<<nb, 256, 0, stream>>>(rqv, rav, out + b0);
    }
}